// Round 3
// baseline (1442.412 us; speedup 1.0000x reference)
//
#include <hip/hip_runtime.h>
#include <hip/hip_bf16.h>

#define DD 128
#define HH 6

// ---------------- encoder: x = relu([pos,norm] @ w1.T + b1) ----------------
__global__ void enc_kernel(const float* __restrict__ pos, const float* __restrict__ nrm,
                           const float* __restrict__ w1, const float* __restrict__ b1,
                           float* __restrict__ x, int n) {
  int i = blockIdx.x;
  int d = threadIdx.x;
  if (i >= n) return;
  float in[6];
  in[0] = pos[i*3+0]; in[1] = pos[i*3+1]; in[2] = pos[i*3+2];
  in[3] = nrm[i*3+0]; in[4] = nrm[i*3+1]; in[5] = nrm[i*3+2];
  const float* wr = w1 + d*6;
  float acc = b1[d];
  #pragma unroll
  for (int k = 0; k < 6; k++) acc = fmaf(in[k], wr[k], acc);
  x[(size_t)i*DD + d] = fmaxf(acc, 0.0f);
}

// ---------------- degree histogram ----------------
__global__ void hist_kernel(const int* __restrict__ dst, int e, int* __restrict__ cnt) {
  int i = blockIdx.x*blockDim.x + threadIdx.x;
  if (i < e) atomicAdd(&cnt[dst[i]], 1);
}

// ---------------- exclusive scan (3 kernels) ----------------
__global__ void scan_blk_kernel(const int* __restrict__ cnt, int* __restrict__ rowptr,
                                int* __restrict__ bsum, int n) {
  __shared__ int s[256];
  int tid = threadIdx.x;
  int i = blockIdx.x*256 + tid;
  int v = (i < n) ? cnt[i] : 0;
  s[tid] = v; __syncthreads();
  #pragma unroll
  for (int off = 1; off < 256; off <<= 1) {
    int t = (tid >= off) ? s[tid-off] : 0;
    __syncthreads();
    s[tid] += t;
    __syncthreads();
  }
  if (i < n) rowptr[i] = s[tid] - v;     // exclusive within block
  if (tid == 255) bsum[blockIdx.x] = s[255];
}

__global__ void scan_top_kernel(int* bsum, int nb) {
  __shared__ int s[256];
  int tid = threadIdx.x;
  int v = (tid < nb) ? bsum[tid] : 0;
  s[tid] = v; __syncthreads();
  #pragma unroll
  for (int off = 1; off < 256; off <<= 1) {
    int t = (tid >= off) ? s[tid-off] : 0;
    __syncthreads();
    s[tid] += t;
    __syncthreads();
  }
  if (tid < nb) bsum[tid] = s[tid] - v;  // exclusive block offsets
}

__global__ void scan_add_kernel(int* rowptr, const int* __restrict__ bsum, int n, int e) {
  int i = blockIdx.x*256 + threadIdx.x;
  if (i < n) rowptr[i] += bsum[blockIdx.x];
  if (i == 0) rowptr[n] = e;
}

__global__ void invdeg_kernel(const int* __restrict__ cnt, float* __restrict__ invdeg, int n) {
  int i = blockIdx.x*blockDim.x + threadIdx.x;
  if (i < n) invdeg[i] = 1.0f / (float)max(cnt[i], 1);
}

// ---------------- CSR fill ----------------
__global__ void fill_kernel(const int* __restrict__ src, const int* __restrict__ dst, int e,
                            const int* __restrict__ rowptr, int* __restrict__ fc,
                            int* __restrict__ esrc, int* __restrict__ eidx) {
  int i = blockIdx.x*blockDim.x + threadIdx.x;
  if (i >= e) return;
  int dd = dst[i];
  int p = rowptr[dd] + atomicAdd(&fc[dd], 1);
  esrc[p] = src[i];
  eidx[p] = i;
}

// ---------------- z = x @ u.T  [N,6] ----------------
__global__ void z_kernel(const float* __restrict__ x, const float* __restrict__ u,
                         float* __restrict__ z, int n) {
  int node = blockIdx.x*4 + (threadIdx.x >> 6);
  int l = threadIdx.x & 63;
  if (node >= n) return;
  float2 v = *(const float2*)&x[(size_t)node*DD + 2*l];
  float p[HH];
  #pragma unroll
  for (int h = 0; h < HH; h++) {
    float2 uv = *(const float2*)&u[h*DD + 2*l];
    p[h] = v.x*uv.x + v.y*uv.y;
  }
  #pragma unroll
  for (int off = 32; off; off >>= 1) {
    #pragma unroll
    for (int h = 0; h < HH; h++) p[h] += __shfl_xor(p[h], off, 64);
  }
  if (l == 0) {
    #pragma unroll
    for (int h = 0; h < HH; h++) z[(size_t)node*HH + h] = p[h];
  }
}

// ---------------- per-edge softmax (deg-divide folded in) ----------------
__global__ void q_kernel(const int* __restrict__ src, const int* __restrict__ dst,
                         const float* __restrict__ z, const float* __restrict__ c,
                         const float* __restrict__ invdeg, float* __restrict__ q, int e) {
  int i = blockIdx.x*blockDim.x + threadIdx.x;
  if (i >= e) return;
  int s = src[i], dd = dst[i];
  float l[HH];
  float m = -1e30f;
  #pragma unroll
  for (int h = 0; h < HH; h++) {
    l[h] = z[(size_t)s*HH + h] - z[(size_t)dd*HH + h] + c[h];
    m = fmaxf(m, l[h]);
  }
  float sum = 0.f;
  #pragma unroll
  for (int h = 0; h < HH; h++) { l[h] = __expf(l[h] - m); sum += l[h]; }
  float r = invdeg[dd] / sum;
  #pragma unroll
  for (int h = 0; h < HH; h++) q[(size_t)i*HH + h] = l[h]*r;
}

// ---------------- CSR aggregation: agg[i][h*128+d] = sum_e q'[e][h]*x[src][d] ----------------
__global__ void agg_kernel(const float* __restrict__ x, const float* __restrict__ q,
                           const int* __restrict__ rowptr, const int* __restrict__ esrc,
                           const int* __restrict__ eidx, float* __restrict__ agg, int n) {
  int i = blockIdx.x;
  int d = threadIdx.x;  // 128 threads
  float acc[HH] = {0.f, 0.f, 0.f, 0.f, 0.f, 0.f};
  int p0 = rowptr[i], p1 = rowptr[i+1];
  for (int p = p0; p < p1; p++) {
    int s = esrc[p];
    const float* qp = &q[(size_t)eidx[p]*HH];
    float xv = x[(size_t)s*DD + d];
    #pragma unroll
    for (int h = 0; h < HH; h++) acc[h] = fmaf(qp[h], xv, acc[h]);
  }
  #pragma unroll
  for (int h = 0; h < HH; h++) agg[(size_t)i*768 + h*DD + d] = acc[h];
}

// ---------------- GEMM: out = relu(agg[n,768] @ Wcat.T + b), Wcat[k=h*128+d][dout]=W[h][dout][d] ----------------
__global__ __launch_bounds__(256) void gemm_kernel(const float* __restrict__ A,
                                                   const float* __restrict__ W,
                                                   const float* __restrict__ bias,
                                                   float* __restrict__ out, int n) {
  __shared__ float At[32][68];   // padded: stride 68 keeps float4 align + spreads banks
  __shared__ float Wt[32][132];
  int tid = threadIdx.x;
  int m0g = blockIdx.x*64;
  int tn = tid & 15, tm = tid >> 4;
  int n0 = tn*8, m0 = tm*4;
  float acc[4][8];
  #pragma unroll
  for (int a = 0; a < 4; a++)
    #pragma unroll
    for (int bb = 0; bb < 8; bb++) acc[a][bb] = 0.f;

  for (int kt = 0; kt < 24; kt++) {
    int k0 = kt*32;
    { // A tile: At[kk][m] = A[m0g+m][k0+kk]
      int m = tid >> 2, kk0 = (tid & 3)*8;
      int gm = m0g + m;
      float4 a0 = {0,0,0,0}, a1 = {0,0,0,0};
      if (gm < n) {
        const float* ap = &A[(size_t)gm*768 + k0 + kk0];
        a0 = *(const float4*)ap;
        a1 = *(const float4*)(ap + 4);
      }
      At[kk0+0][m] = a0.x; At[kk0+1][m] = a0.y; At[kk0+2][m] = a0.z; At[kk0+3][m] = a0.w;
      At[kk0+4][m] = a1.x; At[kk0+5][m] = a1.y; At[kk0+6][m] = a1.z; At[kk0+7][m] = a1.w;
    }
    { // W tile: Wt[kk][nn] = W[h][nn][d0+kk]
      int nn = tid >> 1, kk0 = (tid & 1)*16;
      int h = k0 >> 7, d0 = (k0 & 127) + kk0;
      const float* wp = &W[h*16384 + nn*128 + d0];
      #pragma unroll
      for (int j = 0; j < 16; j += 4) {
        float4 w = *(const float4*)(wp + j);
        Wt[kk0+j+0][nn] = w.x; Wt[kk0+j+1][nn] = w.y;
        Wt[kk0+j+2][nn] = w.z; Wt[kk0+j+3][nn] = w.w;
      }
    }
    __syncthreads();
    #pragma unroll
    for (int kk = 0; kk < 32; kk++) {
      float4 av = *(const float4*)&At[kk][m0];
      float4 w0 = *(const float4*)&Wt[kk][n0];
      float4 w1 = *(const float4*)&Wt[kk][n0+4];
      float am[4] = {av.x, av.y, av.z, av.w};
      float wn[8] = {w0.x, w0.y, w0.z, w0.w, w1.x, w1.y, w1.z, w1.w};
      #pragma unroll
      for (int a = 0; a < 4; a++)
        #pragma unroll
        for (int bb = 0; bb < 8; bb++)
          acc[a][bb] = fmaf(am[a], wn[bb], acc[a][bb]);
    }
    __syncthreads();
  }
  #pragma unroll
  for (int a = 0; a < 4; a++) {
    int gm = m0g + m0 + a;
    if (gm < n) {
      float4 o0, o1;
      o0.x = fmaxf(acc[a][0] + bias[n0+0], 0.f);
      o0.y = fmaxf(acc[a][1] + bias[n0+1], 0.f);
      o0.z = fmaxf(acc[a][2] + bias[n0+2], 0.f);
      o0.w = fmaxf(acc[a][3] + bias[n0+3], 0.f);
      o1.x = fmaxf(acc[a][4] + bias[n0+4], 0.f);
      o1.y = fmaxf(acc[a][5] + bias[n0+5], 0.f);
      o1.z = fmaxf(acc[a][6] + bias[n0+6], 0.f);
      o1.w = fmaxf(acc[a][7] + bias[n0+7], 0.f);
      *(float4*)&out[(size_t)gm*DD + n0]     = o0;
      *(float4*)&out[(size_t)gm*DD + n0 + 4] = o1;
    }
  }
}

// ---------------- final: out = x @ w2.T + b2  [N,3] ----------------
__global__ void fin_kernel(const float* __restrict__ x, const float* __restrict__ w2,
                           const float* __restrict__ b2, float* __restrict__ out, int n) {
  int node = blockIdx.x*4 + (threadIdx.x >> 6);
  int l = threadIdx.x & 63;
  if (node >= n) return;
  float2 v = *(const float2*)&x[(size_t)node*DD + 2*l];
  float p[3];
  #pragma unroll
  for (int o = 0; o < 3; o++) {
    float2 w = *(const float2*)&w2[o*DD + 2*l];
    p[o] = v.x*w.x + v.y*w.y;
  }
  #pragma unroll
  for (int off = 32; off; off >>= 1) {
    #pragma unroll
    for (int o = 0; o < 3; o++) p[o] += __shfl_xor(p[o], off, 64);
  }
  if (l == 0) {
    #pragma unroll
    for (int o = 0; o < 3; o++) out[(size_t)node*3 + o] = p[o] + b2[o];
  }
}

extern "C" void kernel_launch(void* const* d_in, const int* in_sizes, int n_in,
                              void* d_out, int out_size, void* d_ws, size_t ws_size,
                              hipStream_t stream) {
  const float* pos = (const float*)d_in[0];
  const float* nrm = (const float*)d_in[1];
  const int*   ei  = (const int*)d_in[2];
  const float* w1  = (const float*)d_in[3];
  const float* b1  = (const float*)d_in[4];
  const float* w2  = (const float*)d_in[5];
  const float* b2  = (const float*)d_in[6];
  const float* Wg[4] = {(const float*)d_in[7],  (const float*)d_in[11],
                        (const float*)d_in[15], (const float*)d_in[19]};
  const float* uu[4] = {(const float*)d_in[8],  (const float*)d_in[12],
                        (const float*)d_in[16], (const float*)d_in[20]};
  const float* cc[4] = {(const float*)d_in[9],  (const float*)d_in[13],
                        (const float*)d_in[17], (const float*)d_in[21]};
  const float* bg[4] = {(const float*)d_in[10], (const float*)d_in[14],
                        (const float*)d_in[18], (const float*)d_in[22]};
  int n = in_sizes[0] / 3;
  int e = in_sizes[2] / 2;
  const int* src = ei;
  const int* dst = ei + e;

  // workspace carve (aligned to 256B)
  char* p = (char*)d_ws;
  auto alloc = [&](size_t bytes) -> void* {
    void* r = (void*)p;
    p += (bytes + 255) & ~(size_t)255;
    return r;
  };
  float* xa     = (float*)alloc((size_t)n*128*4);
  float* xb     = (float*)alloc((size_t)n*128*4);
  float* agg    = (float*)alloc((size_t)n*768*4);
  float* qbuf   = (float*)alloc((size_t)e*6*4);
  float* zbuf   = (float*)alloc((size_t)n*6*4);
  float* invdeg = (float*)alloc((size_t)n*4);
  int*   cnt    = (int*)alloc((size_t)n*4);
  int*   rowptr = (int*)alloc((size_t)(n+1)*4);
  int*   fc     = (int*)alloc((size_t)n*4);
  int*   esrc   = (int*)alloc((size_t)e*4);
  int*   eidx   = (int*)alloc((size_t)e*4);
  int*   bsum   = (int*)alloc(4096);

  hipMemsetAsync(cnt, 0, (size_t)n*4, stream);
  hipMemsetAsync(fc,  0, (size_t)n*4, stream);

  int eb = (e + 255)/256;
  int nb = (n + 255)/256;

  enc_kernel<<<n, 128, 0, stream>>>(pos, nrm, w1, b1, xa, n);
  hist_kernel<<<eb, 256, 0, stream>>>(dst, e, cnt);
  scan_blk_kernel<<<nb, 256, 0, stream>>>(cnt, rowptr, bsum, n);
  scan_top_kernel<<<1, 256, 0, stream>>>(bsum, nb);
  scan_add_kernel<<<nb, 256, 0, stream>>>(rowptr, bsum, n, e);
  invdeg_kernel<<<nb, 256, 0, stream>>>(cnt, invdeg, n);
  fill_kernel<<<eb, 256, 0, stream>>>(src, dst, e, rowptr, fc, esrc, eidx);

  float* xin = xa;
  float* xout = xb;
  for (int l = 0; l < 4; l++) {
    z_kernel<<<(n+3)/4, 256, 0, stream>>>(xin, uu[l], zbuf, n);
    q_kernel<<<eb, 256, 0, stream>>>(src, dst, zbuf, cc[l], invdeg, qbuf, e);
    agg_kernel<<<n, 128, 0, stream>>>(xin, qbuf, rowptr, esrc, eidx, agg, n);
    gemm_kernel<<<(n+63)/64, 256, 0, stream>>>(agg, Wg[l], bg[l], xout, n);
    float* t = xin; xin = xout; xout = t;
  }
  fin_kernel<<<(n+3)/4, 256, 0, stream>>>(xin, w2, b2, (float*)d_out, n);
}

// Round 6
// 1131.637 us; speedup vs baseline: 1.2746x; 1.2746x over previous
//
#include <hip/hip_runtime.h>
#include <hip/hip_fp16.h>

#define DD 128
#define HH 6

typedef _Float16 f16;
typedef _Float16 f16x2 __attribute__((ext_vector_type(2)));
typedef _Float16 f16x8 __attribute__((ext_vector_type(8)));
typedef float f32x4 __attribute__((ext_vector_type(4)));

// ---------------- encoder: x = relu([pos,norm] @ w1.T + b1) -> fp16 ----------------
__global__ void enc_kernel(const float* __restrict__ pos, const float* __restrict__ nrm,
                           const float* __restrict__ w1, const float* __restrict__ b1,
                           f16* __restrict__ x, int n) {
  int i = blockIdx.x;
  int d = threadIdx.x;
  if (i >= n) return;
  float in[6];
  in[0] = pos[i*3+0]; in[1] = pos[i*3+1]; in[2] = pos[i*3+2];
  in[3] = nrm[i*3+0]; in[4] = nrm[i*3+1]; in[5] = nrm[i*3+2];
  const float* wr = w1 + d*6;
  float acc = b1[d];
  #pragma unroll
  for (int k = 0; k < 6; k++) acc = fmaf(in[k], wr[k], acc);
  x[(size_t)i*DD + d] = (f16)fmaxf(acc, 0.0f);
}

// ---------------- degree histogram ----------------
__global__ void hist_kernel(const int* __restrict__ dst, int e, int* __restrict__ cnt) {
  int i = blockIdx.x*blockDim.x + threadIdx.x;
  if (i < e) atomicAdd(&cnt[dst[i]], 1);
}

// ---------------- exclusive scan (3 kernels) ----------------
__global__ void scan_blk_kernel(const int* __restrict__ cnt, int* __restrict__ rowptr,
                                int* __restrict__ bsum, int n) {
  __shared__ int s[256];
  int tid = threadIdx.x;
  int i = blockIdx.x*256 + tid;
  int v = (i < n) ? cnt[i] : 0;
  s[tid] = v; __syncthreads();
  #pragma unroll
  for (int off = 1; off < 256; off <<= 1) {
    int t = (tid >= off) ? s[tid-off] : 0;
    __syncthreads();
    s[tid] += t;
    __syncthreads();
  }
  if (i < n) rowptr[i] = s[tid] - v;
  if (tid == 255) bsum[blockIdx.x] = s[255];
}

__global__ void scan_top_kernel(int* bsum, int nb) {
  __shared__ int s[256];
  int tid = threadIdx.x;
  int v = (tid < nb) ? bsum[tid] : 0;
  s[tid] = v; __syncthreads();
  #pragma unroll
  for (int off = 1; off < 256; off <<= 1) {
    int t = (tid >= off) ? s[tid-off] : 0;
    __syncthreads();
    s[tid] += t;
    __syncthreads();
  }
  if (tid < nb) bsum[tid] = s[tid] - v;
}

__global__ void scan_add_kernel(int* rowptr, const int* __restrict__ bsum, int n, int e) {
  int i = blockIdx.x*256 + threadIdx.x;
  if (i < n) rowptr[i] += bsum[blockIdx.x];
  if (i == 0) rowptr[n] = e;
}

__global__ void invdeg_kernel(const int* __restrict__ cnt, float* __restrict__ invdeg, int n) {
  int i = blockIdx.x*blockDim.x + threadIdx.x;
  if (i < n) invdeg[i] = 1.0f / (float)max(cnt[i], 1);
}

// ---------------- CSR fill: esrc in CSR order + epos (edge -> CSR slot) ----------------
__global__ void fill_kernel(const int* __restrict__ src, const int* __restrict__ dst, int e,
                            const int* __restrict__ rowptr, int* __restrict__ fc,
                            int* __restrict__ esrc, int* __restrict__ epos) {
  int i = blockIdx.x*blockDim.x + threadIdx.x;
  if (i >= e) return;
  int dd = dst[i];
  int p = rowptr[dd] + atomicAdd(&fc[dd], 1);
  esrc[p] = src[i];
  epos[i] = p;
}

// ---------------- z = x @ u.T  [N,6]  (x fp16) ----------------
__global__ void z_kernel(const f16* __restrict__ x, const float* __restrict__ u,
                         float* __restrict__ z, int n) {
  int node = blockIdx.x*4 + (threadIdx.x >> 6);
  int l = threadIdx.x & 63;
  if (node >= n) return;
  f16x2 v = *(const f16x2*)&x[(size_t)node*DD + 2*l];
  float vx = (float)v[0], vy = (float)v[1];
  float p[HH];
  #pragma unroll
  for (int h = 0; h < HH; h++) {
    float2 uv = *(const float2*)&u[h*DD + 2*l];
    p[h] = vx*uv.x + vy*uv.y;
  }
  #pragma unroll
  for (int off = 32; off; off >>= 1) {
    #pragma unroll
    for (int h = 0; h < HH; h++) p[h] += __shfl_xor(p[h], off, 64);
  }
  if (l == 0) {
    #pragma unroll
    for (int h = 0; h < HH; h++) z[(size_t)node*HH + h] = p[h];
  }
}

// ---------------- per-edge softmax -> fp16 q in CSR order (deg-divide folded) ----------------
__global__ void q_kernel(const int* __restrict__ src, const int* __restrict__ dst,
                         const float* __restrict__ z, const float* __restrict__ c,
                         const float* __restrict__ invdeg, const int* __restrict__ epos,
                         f16* __restrict__ qcsr, int e) {
  int i = blockIdx.x*blockDim.x + threadIdx.x;
  if (i >= e) return;
  int s = src[i], dd = dst[i];
  float l[HH];
  float m = -1e30f;
  #pragma unroll
  for (int h = 0; h < HH; h++) {
    l[h] = z[(size_t)s*HH + h] - z[(size_t)dd*HH + h] + c[h];
    m = fmaxf(m, l[h]);
  }
  float sum = 0.f;
  #pragma unroll
  for (int h = 0; h < HH; h++) { l[h] = __expf(l[h] - m); sum += l[h]; }
  float r = invdeg[dd] / sum;
  size_t p = (size_t)epos[i]*HH;
  f16x2 o0 = {(f16)(l[0]*r), (f16)(l[1]*r)};
  f16x2 o1 = {(f16)(l[2]*r), (f16)(l[3]*r)};
  f16x2 o2 = {(f16)(l[4]*r), (f16)(l[5]*r)};
  *(f16x2*)&qcsr[p+0] = o0;
  *(f16x2*)&qcsr[p+2] = o1;
  *(f16x2*)&qcsr[p+4] = o2;
}

// ---------------- CSR aggregation: agg[i][h*128+d] = sum_p q[p][h]*x[esrc[p]][d] ----------------
// 4 nodes/block, 1 wave each; thread owns d = 2t, 2t+1
__global__ __launch_bounds__(256) void agg_kernel(const f16* __restrict__ x,
                           const f16* __restrict__ qcsr,
                           const int* __restrict__ rowptr, const int* __restrict__ esrc,
                           f16* __restrict__ agg, int n) {
  int node = blockIdx.x*4 + (threadIdx.x >> 6);
  int t = threadIdx.x & 63;
  if (node >= n) return;
  float acc[HH][2];
  #pragma unroll
  for (int h = 0; h < HH; h++) { acc[h][0] = 0.f; acc[h][1] = 0.f; }
  int p0 = rowptr[node], p1 = rowptr[node+1];
  for (int p = p0; p < p1; p++) {
    int s = esrc[p];
    const f16x2* qp = (const f16x2*)(qcsr + (size_t)p*HH);
    f16x2 q01 = qp[0], q23 = qp[1], q45 = qp[2];
    f16x2 xv = *(const f16x2*)&x[(size_t)s*DD + 2*t];
    float x0 = (float)xv[0], x1 = (float)xv[1];
    float qh[HH] = {(float)q01[0], (float)q01[1], (float)q23[0],
                    (float)q23[1], (float)q45[0], (float)q45[1]};
    #pragma unroll
    for (int h = 0; h < HH; h++) {
      acc[h][0] = fmaf(qh[h], x0, acc[h][0]);
      acc[h][1] = fmaf(qh[h], x1, acc[h][1]);
    }
  }
  #pragma unroll
  for (int h = 0; h < HH; h++) {
    f16x2 o = {(f16)acc[h][0], (f16)acc[h][1]};
    *(f16x2*)&agg[(size_t)node*768 + h*DD + 2*t] = o;
  }
}

// ---------------- W concat+convert: Wc[nr][h*128+d] = (f16)W[h][nr][d] ----------------
__global__ void wc_kernel(const float* __restrict__ W, f16* __restrict__ Wc) {
  int id = blockIdx.x*256 + threadIdx.x;
  if (id >= HH*DD*DD) return;
  int h = id >> 14, rem = id & 16383, nr = rem >> 7, d = rem & 127;
  Wc[(size_t)nr*768 + h*DD + d] = (f16)W[id];
}

// ---------------- MFMA GEMM: xout = relu(agg[n,768] @ Wc.T + bias) -> fp16 ----------------
// no LDS: B (196KB) is L2-resident; A streamed. 4 waves/block, wave = 16 rows x 128 cols.
__global__ __launch_bounds__(256) void gemm_kernel(const f16* __restrict__ A,
                                                   const f16* __restrict__ Wc,
                                                   const float* __restrict__ bias,
                                                   f16* __restrict__ xout, int n) {
  int wave = threadIdx.x >> 6;
  int l = threadIdx.x & 63;
  int r16 = l & 15, kc = l >> 4;
  int m_base = blockIdx.x*64 + wave*16;
  int ar = m_base + r16; if (ar > n-1) ar = n-1;   // clamp loads; stores guarded
  const f16* Ap = A  + (size_t)ar*768 + kc*8;
  const f16* Wp = Wc + (size_t)r16*768 + kc*8;
  f32x4 acc[8];
  #pragma unroll
  for (int j = 0; j < 8; j++) acc[j] = (f32x4){0.f, 0.f, 0.f, 0.f};
  for (int t = 0; t < 24; t++) {
    f16x8 a = *(const f16x8*)(Ap + t*32);
    #pragma unroll
    for (int j = 0; j < 8; j++) {
      f16x8 b = *(const f16x8*)(Wp + (size_t)j*16*768 + t*32);
      acc[j] = __builtin_amdgcn_mfma_f32_16x16x32_f16(a, b, acc[j], 0, 0, 0);
    }
  }
  int orow = m_base + (l >> 4)*4;
  #pragma unroll
  for (int j = 0; j < 8; j++) {
    int col = j*16 + (l & 15);
    float bv = bias[col];
    #pragma unroll
    for (int r = 0; r < 4; r++) {
      int gm = orow + r;
      if (gm < n) {
        float v = acc[j][r] + bv;
        xout[(size_t)gm*DD + col] = (f16)fmaxf(v, 0.f);
      }
    }
  }
}

// ---------------- final: out = x @ w2.T + b2  [N,3] (x fp16) ----------------
__global__ void fin_kernel(const f16* __restrict__ x, const float* __restrict__ w2,
                           const float* __restrict__ b2, float* __restrict__ out, int n) {
  int node = blockIdx.x*4 + (threadIdx.x >> 6);
  int l = threadIdx.x & 63;
  if (node >= n) return;
  f16x2 v = *(const f16x2*)&x[(size_t)node*DD + 2*l];
  float vx = (float)v[0], vy = (float)v[1];
  float p[3];
  #pragma unroll
  for (int o = 0; o < 3; o++) {
    float2 w = *(const float2*)&w2[o*DD + 2*l];
    p[o] = vx*w.x + vy*w.y;
  }
  #pragma unroll
  for (int off = 32; off; off >>= 1) {
    #pragma unroll
    for (int o = 0; o < 3; o++) p[o] += __shfl_xor(p[o], off, 64);
  }
  if (l == 0) {
    #pragma unroll
    for (int o = 0; o < 3; o++) out[(size_t)node*3 + o] = p[o] + b2[o];
  }
}

extern "C" void kernel_launch(void* const* d_in, const int* in_sizes, int n_in,
                              void* d_out, int out_size, void* d_ws, size_t ws_size,
                              hipStream_t stream) {
  const float* pos = (const float*)d_in[0];
  const float* nrm = (const float*)d_in[1];
  const int*   ei  = (const int*)d_in[2];
  const float* w1  = (const float*)d_in[3];
  const float* b1  = (const float*)d_in[4];
  const float* w2  = (const float*)d_in[5];
  const float* b2  = (const float*)d_in[6];
  const float* Wg[4] = {(const float*)d_in[7],  (const float*)d_in[11],
                        (const float*)d_in[15], (const float*)d_in[19]};
  const float* uu[4] = {(const float*)d_in[8],  (const float*)d_in[12],
                        (const float*)d_in[16], (const float*)d_in[20]};
  const float* cc[4] = {(const float*)d_in[9],  (const float*)d_in[13],
                        (const float*)d_in[17], (const float*)d_in[21]};
  const float* bg[4] = {(const float*)d_in[10], (const float*)d_in[14],
                        (const float*)d_in[18], (const float*)d_in[22]};
  int n = in_sizes[0] / 3;
  int e = in_sizes[2] / 2;
  const int* src = ei;
  const int* dst = ei + e;

  char* p = (char*)d_ws;
  auto alloc = [&](size_t bytes) -> void* {
    void* r = (void*)p;
    p += (bytes + 255) & ~(size_t)255;
    return r;
  };
  f16*   xa     = (f16*)alloc((size_t)n*DD*2);
  f16*   xb     = (f16*)alloc((size_t)n*DD*2);
  f16*   agg    = (f16*)alloc((size_t)n*768*2);
  f16*   qcsr   = (f16*)alloc((size_t)e*HH*2);
  f16*   wcb    = (f16*)alloc((size_t)DD*768*2);
  float* zbuf   = (float*)alloc((size_t)n*HH*4);
  float* invdeg = (float*)alloc((size_t)n*4);
  int*   cnt    = (int*)alloc((size_t)n*4);
  int*   rowptr = (int*)alloc((size_t)(n+1)*4);
  int*   fc     = (int*)alloc((size_t)n*4);
  int*   esrc   = (int*)alloc((size_t)e*4);
  int*   epos   = (int*)alloc((size_t)e*4);
  int*   bsum   = (int*)alloc(4096);

  hipMemsetAsync(cnt, 0, (size_t)n*4, stream);
  hipMemsetAsync(fc,  0, (size_t)n*4, stream);

  int eb = (e + 255)/256;
  int nb = (n + 255)/256;

  enc_kernel<<<n, 128, 0, stream>>>(pos, nrm, w1, b1, xa, n);
  hist_kernel<<<eb, 256, 0, stream>>>(dst, e, cnt);
  scan_blk_kernel<<<nb, 256, 0, stream>>>(cnt, rowptr, bsum, n);
  scan_top_kernel<<<1, 256, 0, stream>>>(bsum, nb);
  scan_add_kernel<<<nb, 256, 0, stream>>>(rowptr, bsum, n, e);
  invdeg_kernel<<<nb, 256, 0, stream>>>(cnt, invdeg, n);
  fill_kernel<<<eb, 256, 0, stream>>>(src, dst, e, rowptr, fc, esrc, epos);

  f16* xin = xa;
  f16* xout = xb;
  for (int l = 0; l < 4; l++) {
    wc_kernel<<<(HH*DD*DD + 255)/256, 256, 0, stream>>>(Wg[l], wcb);
    z_kernel<<<(n+3)/4, 256, 0, stream>>>(xin, uu[l], zbuf, n);
    q_kernel<<<eb, 256, 0, stream>>>(src, dst, zbuf, cc[l], invdeg, epos, qcsr, e);
    agg_kernel<<<(n+3)/4, 256, 0, stream>>>(xin, qcsr, rowptr, esrc, agg, n);
    gemm_kernel<<<(n+63)/64, 256, 0, stream>>>(agg, wcb, bg[l], xout, n);
    f16* t = xin; xin = xout; xout = t;
  }
  fin_kernel<<<(n+3)/4, 256, 0, stream>>>(xin, w2, b2, (float*)d_out, n);
}

// Round 7
// 829.076 us; speedup vs baseline: 1.7398x; 1.3649x over previous
//
#include <hip/hip_runtime.h>
#include <hip/hip_fp16.h>

#define DD 128
#define HH 6

typedef _Float16 f16;
typedef _Float16 f16x2 __attribute__((ext_vector_type(2)));
typedef _Float16 f16x8 __attribute__((ext_vector_type(8)));
typedef float f32x4 __attribute__((ext_vector_type(4)));

// ---------------- encoder: x = relu([pos,norm] @ w1.T + b1) -> fp16 ----------------
__global__ void enc_kernel(const float* __restrict__ pos, const float* __restrict__ nrm,
                           const float* __restrict__ w1, const float* __restrict__ b1,
                           f16* __restrict__ x, int n) {
  int i = blockIdx.x;
  int d = threadIdx.x;
  if (i >= n) return;
  float in[6];
  in[0] = pos[i*3+0]; in[1] = pos[i*3+1]; in[2] = pos[i*3+2];
  in[3] = nrm[i*3+0]; in[4] = nrm[i*3+1]; in[5] = nrm[i*3+2];
  const float* wr = w1 + d*6;
  float acc = b1[d];
  #pragma unroll
  for (int k = 0; k < 6; k++) acc = fmaf(in[k], wr[k], acc);
  x[(size_t)i*DD + d] = (f16)fmaxf(acc, 0.0f);
}

// ---------------- degree histogram ----------------
__global__ void hist_kernel(const int* __restrict__ dst, int e, int* __restrict__ cnt) {
  int i = blockIdx.x*blockDim.x + threadIdx.x;
  if (i < e) atomicAdd(&cnt[dst[i]], 1);
}

// ---------------- exclusive scan (3 kernels) ----------------
__global__ void scan_blk_kernel(const int* __restrict__ cnt, int* __restrict__ rowptr,
                                int* __restrict__ bsum, int n) {
  __shared__ int s[256];
  int tid = threadIdx.x;
  int i = blockIdx.x*256 + tid;
  int v = (i < n) ? cnt[i] : 0;
  s[tid] = v; __syncthreads();
  #pragma unroll
  for (int off = 1; off < 256; off <<= 1) {
    int t = (tid >= off) ? s[tid-off] : 0;
    __syncthreads();
    s[tid] += t;
    __syncthreads();
  }
  if (i < n) rowptr[i] = s[tid] - v;
  if (tid == 255) bsum[blockIdx.x] = s[255];
}

__global__ void scan_top_kernel(int* bsum, int nb) {
  __shared__ int s[256];
  int tid = threadIdx.x;
  int v = (tid < nb) ? bsum[tid] : 0;
  s[tid] = v; __syncthreads();
  #pragma unroll
  for (int off = 1; off < 256; off <<= 1) {
    int t = (tid >= off) ? s[tid-off] : 0;
    __syncthreads();
    s[tid] += t;
    __syncthreads();
  }
  if (tid < nb) bsum[tid] = s[tid] - v;
}

__global__ void scan_add_kernel(int* rowptr, const int* __restrict__ bsum, int n, int e) {
  int i = blockIdx.x*256 + threadIdx.x;
  if (i < n) rowptr[i] += bsum[blockIdx.x];
  if (i == 0) rowptr[n] = e;
}

__global__ void invdeg_kernel(const int* __restrict__ cnt, float* __restrict__ invdeg, int n) {
  int i = blockIdx.x*blockDim.x + threadIdx.x;
  if (i < n) invdeg[i] = 1.0f / (float)max(cnt[i], 1);
}

// ---------------- CSR fill: esrc in CSR order + epos (edge -> CSR slot) ----------------
__global__ void fill_kernel(const int* __restrict__ src, const int* __restrict__ dst, int e,
                            const int* __restrict__ rowptr, int* __restrict__ fc,
                            int* __restrict__ esrc, int* __restrict__ epos) {
  int i = blockIdx.x*blockDim.x + threadIdx.x;
  if (i >= e) return;
  int dd = dst[i];
  int p = rowptr[dd] + atomicAdd(&fc[dd], 1);
  esrc[p] = src[i];
  epos[i] = p;
}

// ---------------- z = x @ u.T  [N,6]  (x fp16) ----------------
__global__ void z_kernel(const f16* __restrict__ x, const float* __restrict__ u,
                         float* __restrict__ z, int n) {
  int node = blockIdx.x*4 + (threadIdx.x >> 6);
  int l = threadIdx.x & 63;
  if (node >= n) return;
  f16x2 v = *(const f16x2*)&x[(size_t)node*DD + 2*l];
  float vx = (float)v[0], vy = (float)v[1];
  float p[HH];
  #pragma unroll
  for (int h = 0; h < HH; h++) {
    float2 uv = *(const float2*)&u[h*DD + 2*l];
    p[h] = vx*uv.x + vy*uv.y;
  }
  #pragma unroll
  for (int off = 32; off; off >>= 1) {
    #pragma unroll
    for (int h = 0; h < HH; h++) p[h] += __shfl_xor(p[h], off, 64);
  }
  if (l == 0) {
    #pragma unroll
    for (int h = 0; h < HH; h++) z[(size_t)node*HH + h] = p[h];
  }
}

// ---------------- per-edge softmax -> fp16 q in CSR order (deg-divide folded) ----------------
__global__ void q_kernel(const int* __restrict__ src, const int* __restrict__ dst,
                         const float* __restrict__ z, const float* __restrict__ c,
                         const float* __restrict__ invdeg, const int* __restrict__ epos,
                         f16* __restrict__ qcsr, int e) {
  int i = blockIdx.x*blockDim.x + threadIdx.x;
  if (i >= e) return;
  int s = src[i], dd = dst[i];
  float l[HH];
  float m = -1e30f;
  #pragma unroll
  for (int h = 0; h < HH; h++) {
    l[h] = z[(size_t)s*HH + h] - z[(size_t)dd*HH + h] + c[h];
    m = fmaxf(m, l[h]);
  }
  float sum = 0.f;
  #pragma unroll
  for (int h = 0; h < HH; h++) { l[h] = __expf(l[h] - m); sum += l[h]; }
  float r = invdeg[dd] / sum;
  size_t p = (size_t)epos[i]*HH;
  f16x2 o0 = {(f16)(l[0]*r), (f16)(l[1]*r)};
  f16x2 o1 = {(f16)(l[2]*r), (f16)(l[3]*r)};
  f16x2 o2 = {(f16)(l[4]*r), (f16)(l[5]*r)};
  *(f16x2*)&qcsr[p+0] = o0;
  *(f16x2*)&qcsr[p+2] = o1;
  *(f16x2*)&qcsr[p+4] = o2;
}

// ---------------- CSR aggregation: agg[i][h*128+d] = sum_p q[p][h]*x[esrc[p]][d] ----------------
__global__ __launch_bounds__(256) void agg_kernel(const f16* __restrict__ x,
                           const f16* __restrict__ qcsr,
                           const int* __restrict__ rowptr, const int* __restrict__ esrc,
                           f16* __restrict__ agg, int n) {
  int node = blockIdx.x*4 + (threadIdx.x >> 6);
  int t = threadIdx.x & 63;
  if (node >= n) return;
  float acc[HH][2];
  #pragma unroll
  for (int h = 0; h < HH; h++) { acc[h][0] = 0.f; acc[h][1] = 0.f; }
  int p0 = rowptr[node], p1 = rowptr[node+1];
  for (int p = p0; p < p1; p++) {
    int s = esrc[p];
    const f16x2* qp = (const f16x2*)(qcsr + (size_t)p*HH);
    f16x2 q01 = qp[0], q23 = qp[1], q45 = qp[2];
    f16x2 xv = *(const f16x2*)&x[(size_t)s*DD + 2*t];
    float x0 = (float)xv[0], x1 = (float)xv[1];
    float qh[HH] = {(float)q01[0], (float)q01[1], (float)q23[0],
                    (float)q23[1], (float)q45[0], (float)q45[1]};
    #pragma unroll
    for (int h = 0; h < HH; h++) {
      acc[h][0] = fmaf(qh[h], x0, acc[h][0]);
      acc[h][1] = fmaf(qh[h], x1, acc[h][1]);
    }
  }
  #pragma unroll
  for (int h = 0; h < HH; h++) {
    f16x2 o = {(f16)acc[h][0], (f16)acc[h][1]};
    *(f16x2*)&agg[(size_t)node*768 + h*DD + 2*t] = o;
  }
}

// ---------------- W concat+convert: Wc[nr][h*128+d] = (f16)W[h][nr][d] ----------------
__global__ void wc_kernel(const float* __restrict__ W, f16* __restrict__ Wc) {
  int id = blockIdx.x*256 + threadIdx.x;
  if (id >= HH*DD*DD) return;
  int h = id >> 14, rem = id & 16383, nr = rem >> 7, d = rem & 127;
  Wc[(size_t)nr*768 + h*DD + d] = (f16)W[id];
}

// ---------------- MFMA GEMM (m97-style): xout = relu(agg[n,768] @ Wc.T + bias) ----------------
// 128x128 tile, BK=64, double-buffered global_load_lds(16B), XOR-swizzled LDS
// (inverse-swizzle on global source, swizzle on ds_read — both-sides rule).
// 4 waves in 2x2 grid; wave computes 64x64 via 4x4 16x16x32 MFMA frags.
__global__ __launch_bounds__(256) void gemm_kernel(const f16* __restrict__ A,
                                                   const f16* __restrict__ Wc,
                                                   const float* __restrict__ bias,
                                                   f16* __restrict__ xout, int n) {
  __shared__ char lds[65536];           // A: 2 x 16KB, B: 2 x 16KB
  const int t = threadIdx.x;
  const int l = t & 63;
  const int wave = t >> 6;
  const int wr = wave >> 1, wc = wave & 1;
  const int r16 = l & 15, kc = l >> 4;
  const int m0 = blockIdx.x * 128;

  // staging geometry: dest byte o = i*4096 + t*16 -> row r = i*32 + (t>>3),
  // dest col-byte (t&7)*16; source col-byte = dest ^ ((r&7)<<4)  [inverse swizzle]
  const int sr0 = t >> 3;
  const int scb = (t & 7) * 16;

  auto stage = [&](int ks, int buf) {
    const int k0 = ks * 64;
    char* Ad = lds + buf * 16384 + (size_t)t * 16;
    char* Bd = lds + 32768 + buf * 16384 + (size_t)t * 16;
    #pragma unroll
    for (int i = 0; i < 4; i++) {
      int r = i * 32 + sr0;
      int cs = (scb ^ ((r & 7) << 4)) >> 1;       // source col in elems
      const f16* ga = A  + (size_t)(m0 + r) * 768 + k0 + cs;
      const f16* gb = Wc + (size_t)r * 768 + k0 + cs;
      __builtin_amdgcn_global_load_lds(
          (const __attribute__((address_space(1))) void*)ga,
          (__attribute__((address_space(3))) void*)(Ad + i * 4096), 16, 0, 0);
      __builtin_amdgcn_global_load_lds(
          (const __attribute__((address_space(1))) void*)gb,
          (__attribute__((address_space(3))) void*)(Bd + i * 4096), 16, 0, 0);
    }
  };

  f32x4 acc[4][4];
  #pragma unroll
  for (int m = 0; m < 4; m++)
    #pragma unroll
    for (int nn = 0; nn < 4; nn++) acc[m][nn] = (f32x4){0.f, 0.f, 0.f, 0.f};

  stage(0, 0);
  __syncthreads();

  const int xr = (r16 & 7) << 4;                  // read-side swizzle (row%8)
  for (int ks = 0; ks < 12; ks++) {
    int buf = ks & 1;
    if (ks < 11) stage(ks + 1, buf ^ 1);
    const char* Ab = lds + buf * 16384;
    const char* Bb = lds + 32768 + buf * 16384;
    #pragma unroll
    for (int kk = 0; kk < 2; kk++) {
      int kb = (kk * 64 + kc * 16) ^ xr;
      f16x8 a[4], b[4];
      #pragma unroll
      for (int m = 0; m < 4; m++)
        a[m] = *(const f16x8*)(Ab + (wr*64 + m*16 + r16) * 128 + kb);
      #pragma unroll
      for (int nn = 0; nn < 4; nn++)
        b[nn] = *(const f16x8*)(Bb + (wc*64 + nn*16 + r16) * 128 + kb);
      #pragma unroll
      for (int m = 0; m < 4; m++)
        #pragma unroll
        for (int nn = 0; nn < 4; nn++)
          acc[m][nn] = __builtin_amdgcn_mfma_f32_16x16x32_f16(a[m], b[nn], acc[m][nn], 0, 0, 0);
    }
    __syncthreads();
  }

  #pragma unroll
  for (int nn = 0; nn < 4; nn++) {
    int col = wc*64 + nn*16 + r16;
    float bv = bias[col];
    #pragma unroll
    for (int m = 0; m < 4; m++) {
      int rbase = m0 + wr*64 + m*16 + kc*4;
      #pragma unroll
      for (int rr = 0; rr < 4; rr++) {
        int gm = rbase + rr;
        if (gm < n) xout[(size_t)gm*DD + col] = (f16)fmaxf(acc[m][nn][rr] + bv, 0.f);
      }
    }
  }
}

// ---------------- final: out = x @ w2.T + b2  [N,3] (x fp16) ----------------
__global__ void fin_kernel(const f16* __restrict__ x, const float* __restrict__ w2,
                           const float* __restrict__ b2, float* __restrict__ out, int n) {
  int node = blockIdx.x*4 + (threadIdx.x >> 6);
  int l = threadIdx.x & 63;
  if (node >= n) return;
  f16x2 v = *(const f16x2*)&x[(size_t)node*DD + 2*l];
  float vx = (float)v[0], vy = (float)v[1];
  float p[3];
  #pragma unroll
  for (int o = 0; o < 3; o++) {
    float2 w = *(const float2*)&w2[o*DD + 2*l];
    p[o] = vx*w.x + vy*w.y;
  }
  #pragma unroll
  for (int off = 32; off; off >>= 1) {
    #pragma unroll
    for (int o = 0; o < 3; o++) p[o] += __shfl_xor(p[o], off, 64);
  }
  if (l == 0) {
    #pragma unroll
    for (int o = 0; o < 3; o++) out[(size_t)node*3 + o] = p[o] + b2[o];
  }
}

extern "C" void kernel_launch(void* const* d_in, const int* in_sizes, int n_in,
                              void* d_out, int out_size, void* d_ws, size_t ws_size,
                              hipStream_t stream) {
  const float* pos = (const float*)d_in[0];
  const float* nrm = (const float*)d_in[1];
  const int*   ei  = (const int*)d_in[2];
  const float* w1  = (const float*)d_in[3];
  const float* b1  = (const float*)d_in[4];
  const float* w2  = (const float*)d_in[5];
  const float* b2  = (const float*)d_in[6];
  const float* Wg[4] = {(const float*)d_in[7],  (const float*)d_in[11],
                        (const float*)d_in[15], (const float*)d_in[19]};
  const float* uu[4] = {(const float*)d_in[8],  (const float*)d_in[12],
                        (const float*)d_in[16], (const float*)d_in[20]};
  const float* cc[4] = {(const float*)d_in[9],  (const float*)d_in[13],
                        (const float*)d_in[17], (const float*)d_in[21]};
  const float* bg[4] = {(const float*)d_in[10], (const float*)d_in[14],
                        (const float*)d_in[18], (const float*)d_in[22]};
  int n = in_sizes[0] / 3;
  int e = in_sizes[2] / 2;
  const int* src = ei;
  const int* dst = ei + e;

  char* p = (char*)d_ws;
  auto alloc = [&](size_t bytes) -> void* {
    void* r = (void*)p;
    p += (bytes + 255) & ~(size_t)255;
    return r;
  };
  f16*   xa     = (f16*)alloc((size_t)n*DD*2);
  f16*   xb     = (f16*)alloc((size_t)n*DD*2);
  f16*   agg    = (f16*)alloc((size_t)n*768*2 + 131072);  // slack for tail-tile OOB reads
  f16*   qcsr   = (f16*)alloc((size_t)e*HH*2);
  f16*   wcb    = (f16*)alloc((size_t)DD*768*2);
  float* zbuf   = (float*)alloc((size_t)n*HH*4);
  float* invdeg = (float*)alloc((size_t)n*4);
  int*   cnt    = (int*)alloc((size_t)n*4);
  int*   rowptr = (int*)alloc((size_t)(n+1)*4);
  int*   fc     = (int*)alloc((size_t)n*4);
  int*   esrc   = (int*)alloc((size_t)e*4);
  int*   epos   = (int*)alloc((size_t)e*4);
  int*   bsum   = (int*)alloc(4096);

  hipMemsetAsync(cnt, 0, (size_t)n*4, stream);
  hipMemsetAsync(fc,  0, (size_t)n*4, stream);

  int eb = (e + 255)/256;
  int nb = (n + 255)/256;

  enc_kernel<<<n, 128, 0, stream>>>(pos, nrm, w1, b1, xa, n);
  hist_kernel<<<eb, 256, 0, stream>>>(dst, e, cnt);
  scan_blk_kernel<<<nb, 256, 0, stream>>>(cnt, rowptr, bsum, n);
  scan_top_kernel<<<1, 256, 0, stream>>>(bsum, nb);
  scan_add_kernel<<<nb, 256, 0, stream>>>(rowptr, bsum, n, e);
  invdeg_kernel<<<nb, 256, 0, stream>>>(cnt, invdeg, n);
  fill_kernel<<<eb, 256, 0, stream>>>(src, dst, e, rowptr, fc, esrc, epos);

  f16* xin = xa;
  f16* xout = xb;
  for (int l = 0; l < 4; l++) {
    wc_kernel<<<(HH*DD*DD + 255)/256, 256, 0, stream>>>(Wg[l], wcb);
    z_kernel<<<(n+3)/4, 256, 0, stream>>>(xin, uu[l], zbuf, n);
    q_kernel<<<eb, 256, 0, stream>>>(src, dst, zbuf, cc[l], invdeg, epos, qcsr, e);
    agg_kernel<<<(n+3)/4, 256, 0, stream>>>(xin, qcsr, rowptr, esrc, agg, n);
    gemm_kernel<<<(n+127)/128, 256, 0, stream>>>(agg, wcb, bg[l], xout, n);
    f16* t = xin; xin = xout; xout = t;
  }
  fin_kernel<<<(n+3)/4, 256, 0, stream>>>(xin, w2, b2, (float*)d_out, n);
}

// Round 9
// 682.618 us; speedup vs baseline: 2.1131x; 1.2146x over previous
//
#include <hip/hip_runtime.h>
#include <hip/hip_fp16.h>

#define DD 128
#define HH 6

typedef _Float16 f16;
typedef _Float16 f16x2 __attribute__((ext_vector_type(2)));
typedef _Float16 f16x8 __attribute__((ext_vector_type(8)));
typedef float f32x4 __attribute__((ext_vector_type(4)));

// ---------------- encoder: x = relu([pos,norm] @ w1.T + b1) -> fp16 ----------------
__global__ void enc_kernel(const float* __restrict__ pos, const float* __restrict__ nrm,
                           const float* __restrict__ w1, const float* __restrict__ b1,
                           f16* __restrict__ x, int n) {
  int i = blockIdx.x;
  int d = threadIdx.x;
  if (i >= n) return;
  float in[6];
  in[0] = pos[i*3+0]; in[1] = pos[i*3+1]; in[2] = pos[i*3+2];
  in[3] = nrm[i*3+0]; in[4] = nrm[i*3+1]; in[5] = nrm[i*3+2];
  const float* wr = w1 + d*6;
  float acc = b1[d];
  #pragma unroll
  for (int k = 0; k < 6; k++) acc = fmaf(in[k], wr[k], acc);
  x[(size_t)i*DD + d] = (f16)fmaxf(acc, 0.0f);
}

// ---------------- degree histogram ----------------
__global__ void hist_kernel(const int* __restrict__ dst, int e, int* __restrict__ cnt) {
  int i = blockIdx.x*blockDim.x + threadIdx.x;
  if (i < e) atomicAdd(&cnt[dst[i]], 1);
}

// ---------------- exclusive scan (3 kernels) ----------------
__global__ void scan_blk_kernel(const int* __restrict__ cnt, int* __restrict__ rowptr,
                                int* __restrict__ bsum, int n) {
  __shared__ int s[256];
  int tid = threadIdx.x;
  int i = blockIdx.x*256 + tid;
  int v = (i < n) ? cnt[i] : 0;
  s[tid] = v; __syncthreads();
  #pragma unroll
  for (int off = 1; off < 256; off <<= 1) {
    int t = (tid >= off) ? s[tid-off] : 0;
    __syncthreads();
    s[tid] += t;
    __syncthreads();
  }
  if (i < n) rowptr[i] = s[tid] - v;
  if (tid == 255) bsum[blockIdx.x] = s[255];
}

__global__ void scan_top_kernel(int* bsum, int nb) {
  __shared__ int s[256];
  int tid = threadIdx.x;
  int v = (tid < nb) ? bsum[tid] : 0;
  s[tid] = v; __syncthreads();
  #pragma unroll
  for (int off = 1; off < 256; off <<= 1) {
    int t = (tid >= off) ? s[tid-off] : 0;
    __syncthreads();
    s[tid] += t;
    __syncthreads();
  }
  if (tid < nb) bsum[tid] = s[tid] - v;
}

// rowptr finalize + invdeg fused
__global__ void scan_add_kernel(int* rowptr, const int* __restrict__ bsum,
                                const int* __restrict__ cnt, float* __restrict__ invdeg,
                                int n, int e) {
  int i = blockIdx.x*256 + threadIdx.x;
  if (i < n) {
    rowptr[i] += bsum[blockIdx.x];
    invdeg[i] = 1.0f / (float)max(cnt[i], 1);
  }
  if (i == 0) rowptr[n] = e;
}

// ---------------- CSR fill: esrc in CSR order + epos (edge -> CSR slot) ----------------
__global__ void fill_kernel(const int* __restrict__ src, const int* __restrict__ dst, int e,
                            const int* __restrict__ rowptr, int* __restrict__ fc,
                            int* __restrict__ esrc, int* __restrict__ epos) {
  int i = blockIdx.x*blockDim.x + threadIdx.x;
  if (i >= e) return;
  int dd = dst[i];
  int p = rowptr[dd] + atomicAdd(&fc[dd], 1);
  esrc[p] = src[i];
  epos[i] = p;
}

// ---------------- z = x @ u.T  [N,6]  (x fp16) ----------------
__global__ void z_kernel(const f16* __restrict__ x, const float* __restrict__ u,
                         float* __restrict__ z, int n) {
  int node = blockIdx.x*4 + (threadIdx.x >> 6);
  int l = threadIdx.x & 63;
  if (node >= n) return;
  f16x2 v = *(const f16x2*)&x[(size_t)node*DD + 2*l];
  float vx = (float)v[0], vy = (float)v[1];
  float p[HH];
  #pragma unroll
  for (int h = 0; h < HH; h++) {
    float2 uv = *(const float2*)&u[h*DD + 2*l];
    p[h] = vx*uv.x + vy*uv.y;
  }
  #pragma unroll
  for (int off = 32; off; off >>= 1) {
    #pragma unroll
    for (int h = 0; h < HH; h++) p[h] += __shfl_xor(p[h], off, 64);
  }
  if (l == 0) {
    #pragma unroll
    for (int h = 0; h < HH; h++) z[(size_t)node*HH + h] = p[h];
  }
}

// ---------------- per-edge softmax -> fp16 q in CSR order (deg-divide folded) ----------------
__global__ void q_kernel(const int* __restrict__ src, const int* __restrict__ dst,
                         const float* __restrict__ z, const float* __restrict__ c,
                         const float* __restrict__ invdeg, const int* __restrict__ epos,
                         f16* __restrict__ qcsr, int e) {
  int i = blockIdx.x*blockDim.x + threadIdx.x;
  if (i >= e) return;
  int s = src[i], dd = dst[i];
  float l[HH];
  float m = -1e30f;
  #pragma unroll
  for (int h = 0; h < HH; h++) {
    l[h] = z[(size_t)s*HH + h] - z[(size_t)dd*HH + h] + c[h];
    m = fmaxf(m, l[h]);
  }
  float sum = 0.f;
  #pragma unroll
  for (int h = 0; h < HH; h++) { l[h] = __expf(l[h] - m); sum += l[h]; }
  float r = invdeg[dd] / sum;
  size_t p = (size_t)epos[i]*HH;
  f16x2 o0 = {(f16)(l[0]*r), (f16)(l[1]*r)};
  f16x2 o1 = {(f16)(l[2]*r), (f16)(l[3]*r)};
  f16x2 o2 = {(f16)(l[4]*r), (f16)(l[5]*r)};
  *(f16x2*)&qcsr[p+0] = o0;
  *(f16x2*)&qcsr[p+2] = o1;
  *(f16x2*)&qcsr[p+4] = o2;
}

// ---------------- CSR aggregation: agg[i][h*128+d] = sum_p q[p][h]*x[esrc[p]][d] ----------------
// unroll-4 edge loop (MLP), nontemporal agg stores (no RFO)
__global__ __launch_bounds__(256) void agg_kernel(const f16* __restrict__ x,
                           const f16* __restrict__ qcsr,
                           const int* __restrict__ rowptr, const int* __restrict__ esrc,
                           f16* __restrict__ agg, int n) {
  int node = blockIdx.x*4 + (threadIdx.x >> 6);
  int t = threadIdx.x & 63;
  if (node >= n) return;
  float acc0[HH] = {0,0,0,0,0,0};
  float acc1[HH] = {0,0,0,0,0,0};
  int p0 = rowptr[node], p1 = rowptr[node+1];
  int p = p0;
  for (; p + 4 <= p1; p += 4) {
    int s[4];
    #pragma unroll
    for (int u = 0; u < 4; u++) s[u] = esrc[p+u];
    f16x2 xv[4];
    #pragma unroll
    for (int u = 0; u < 4; u++) xv[u] = *(const f16x2*)&x[(size_t)s[u]*DD + 2*t];
    const f16x2* qp = (const f16x2*)(qcsr + (size_t)p*HH);
    f16x2 qv[12];
    #pragma unroll
    for (int u = 0; u < 12; u++) qv[u] = qp[u];
    #pragma unroll
    for (int u = 0; u < 4; u++) {
      float x0 = (float)xv[u][0], x1 = (float)xv[u][1];
      float qh[HH] = {(float)qv[u*3+0][0], (float)qv[u*3+0][1],
                      (float)qv[u*3+1][0], (float)qv[u*3+1][1],
                      (float)qv[u*3+2][0], (float)qv[u*3+2][1]};
      #pragma unroll
      for (int h = 0; h < HH; h++) {
        acc0[h] = fmaf(qh[h], x0, acc0[h]);
        acc1[h] = fmaf(qh[h], x1, acc1[h]);
      }
    }
  }
  for (; p < p1; p++) {
    int s = esrc[p];
    const f16x2* qp = (const f16x2*)(qcsr + (size_t)p*HH);
    f16x2 q01 = qp[0], q23 = qp[1], q45 = qp[2];
    f16x2 xv = *(const f16x2*)&x[(size_t)s*DD + 2*t];
    float x0 = (float)xv[0], x1 = (float)xv[1];
    float qh[HH] = {(float)q01[0], (float)q01[1], (float)q23[0],
                    (float)q23[1], (float)q45[0], (float)q45[1]};
    #pragma unroll
    for (int h = 0; h < HH; h++) {
      acc0[h] = fmaf(qh[h], x0, acc0[h]);
      acc1[h] = fmaf(qh[h], x1, acc1[h]);
    }
  }
  #pragma unroll
  for (int h = 0; h < HH; h++) {
    f16x2 o = {(f16)acc0[h], (f16)acc1[h]};
    __builtin_nontemporal_store(__builtin_bit_cast(unsigned, o),
        (unsigned*)&agg[(size_t)node*768 + h*DD + 2*t]);
  }
}

// ---------------- W concat+convert, all 4 layers: Wc[l][nr][h*128+d] = (f16)W_l[h][nr][d] ----------------
__global__ void wc4_kernel(const float* __restrict__ W0, const float* __restrict__ W1,
                           const float* __restrict__ W2, const float* __restrict__ W3,
                           f16* __restrict__ Wc) {
  int id = blockIdx.x*256 + threadIdx.x;
  if (id >= 4*HH*DD*DD) return;
  int l = id / (HH*DD*DD);
  int r = id - l*(HH*DD*DD);
  const float* W = (l == 0) ? W0 : (l == 1) ? W1 : (l == 2) ? W2 : W3;
  int h = r >> 14, rem = r & 16383, nr = rem >> 7, d = rem & 127;
  Wc[(size_t)l*(HH*DD*DD) + (size_t)nr*768 + h*DD + d] = (f16)W[r];
}

// ---------------- MFMA GEMM (m97-style): xout = relu(agg[n,768] @ Wc.T + bias) ----------------
// 128x128 tile, BK=64, double-buffered global_load_lds(16B), XOR-swizzled LDS
// (inverse-swizzle on global source, swizzle on ds_read — both-sides rule).
// 4 waves in 2x2 grid; wave computes 64x64 via 4x4 16x16x32 MFMA frags.
__global__ __launch_bounds__(256) void gemm_kernel(const f16* __restrict__ A,
                                                   const f16* __restrict__ Wc,
                                                   const float* __restrict__ bias,
                                                   f16* __restrict__ xout, int n) {
  __shared__ char lds[65536];           // A: 2 x 16KB, B: 2 x 16KB
  const int t = threadIdx.x;
  const int l = t & 63;
  const int wave = t >> 6;
  const int wr = wave >> 1, wc = wave & 1;
  const int r16 = l & 15, kc = l >> 4;
  const int m0 = blockIdx.x * 128;

  const int sr0 = t >> 3;
  const int scb = (t & 7) * 16;

  auto stage = [&](int ks, int buf) {
    const int k0 = ks * 64;
    char* Ad = lds + buf * 16384 + (size_t)t * 16;
    char* Bd = lds + 32768 + buf * 16384 + (size_t)t * 16;
    #pragma unroll
    for (int i = 0; i < 4; i++) {
      int r = i * 32 + sr0;
      int cs = (scb ^ ((r & 7) << 4)) >> 1;       // source col in elems
      const f16* ga = A  + (size_t)(m0 + r) * 768 + k0 + cs;
      const f16* gb = Wc + (size_t)r * 768 + k0 + cs;
      __builtin_amdgcn_global_load_lds(
          (const __attribute__((address_space(1))) void*)ga,
          (__attribute__((address_space(3))) void*)(Ad + i * 4096), 16, 0, 0);
      __builtin_amdgcn_global_load_lds(
          (const __attribute__((address_space(1))) void*)gb,
          (__attribute__((address_space(3))) void*)(Bd + i * 4096), 16, 0, 0);
    }
  };

  f32x4 acc[4][4];
  #pragma unroll
  for (int m = 0; m < 4; m++)
    #pragma unroll
    for (int nn = 0; nn < 4; nn++) acc[m][nn] = (f32x4){0.f, 0.f, 0.f, 0.f};

  stage(0, 0);
  __syncthreads();

  const int xr = (r16 & 7) << 4;
  for (int ks = 0; ks < 12; ks++) {
    int buf = ks & 1;
    if (ks < 11) stage(ks + 1, buf ^ 1);
    const char* Ab = lds + buf * 16384;
    const char* Bb = lds + 32768 + buf * 16384;
    #pragma unroll
    for (int kk = 0; kk < 2; kk++) {
      int kb = (kk * 64 + kc * 16) ^ xr;
      f16x8 a[4], b[4];
      #pragma unroll
      for (int m = 0; m < 4; m++)
        a[m] = *(const f16x8*)(Ab + (wr*64 + m*16 + r16) * 128 + kb);
      #pragma unroll
      for (int nn = 0; nn < 4; nn++)
        b[nn] = *(const f16x8*)(Bb + (wc*64 + nn*16 + r16) * 128 + kb);
      #pragma unroll
      for (int m = 0; m < 4; m++)
        #pragma unroll
        for (int nn = 0; nn < 4; nn++)
          acc[m][nn] = __builtin_amdgcn_mfma_f32_16x16x32_f16(a[m], b[nn], acc[m][nn], 0, 0, 0);
    }
    __syncthreads();
  }

  #pragma unroll
  for (int nn = 0; nn < 4; nn++) {
    int col = wc*64 + nn*16 + r16;
    float bv = bias[col];
    #pragma unroll
    for (int m = 0; m < 4; m++) {
      int rbase = m0 + wr*64 + m*16 + kc*4;
      #pragma unroll
      for (int rr = 0; rr < 4; rr++) {
        int gm = rbase + rr;
        if (gm < n) xout[(size_t)gm*DD + col] = (f16)fmaxf(acc[m][nn][rr] + bv, 0.f);
      }
    }
  }
}

// ---------------- final: out = x @ w2.T + b2  [N,3] (x fp16) ----------------
__global__ void fin_kernel(const f16* __restrict__ x, const float* __restrict__ w2,
                           const float* __restrict__ b2, float* __restrict__ out, int n) {
  int node = blockIdx.x*4 + (threadIdx.x >> 6);
  int l = threadIdx.x & 63;
  if (node >= n) return;
  f16x2 v = *(const f16x2*)&x[(size_t)node*DD + 2*l];
  float vx = (float)v[0], vy = (float)v[1];
  float p[3];
  #pragma unroll
  for (int o = 0; o < 3; o++) {
    float2 w = *(const float2*)&w2[o*DD + 2*l];
    p[o] = vx*w.x + vy*w.y;
  }
  #pragma unroll
  for (int off = 32; off; off >>= 1) {
    #pragma unroll
    for (int o = 0; o < 3; o++) p[o] += __shfl_xor(p[o], off, 64);
  }
  if (l == 0) {
    #pragma unroll
    for (int o = 0; o < 3; o++) out[(size_t)node*3 + o] = p[o] + b2[o];
  }
}

extern "C" void kernel_launch(void* const* d_in, const int* in_sizes, int n_in,
                              void* d_out, int out_size, void* d_ws, size_t ws_size,
                              hipStream_t stream) {
  const float* pos = (const float*)d_in[0];
  const float* nrm = (const float*)d_in[1];
  const int*   ei  = (const int*)d_in[2];
  const float* w1  = (const float*)d_in[3];
  const float* b1  = (const float*)d_in[4];
  const float* w2  = (const float*)d_in[5];
  const float* b2  = (const float*)d_in[6];
  const float* Wg[4] = {(const float*)d_in[7],  (const float*)d_in[11],
                        (const float*)d_in[15], (const float*)d_in[19]};
  const float* uu[4] = {(const float*)d_in[8],  (const float*)d_in[12],
                        (const float*)d_in[16], (const float*)d_in[20]};
  const float* cc[4] = {(const float*)d_in[9],  (const float*)d_in[13],
                        (const float*)d_in[17], (const float*)d_in[21]};
  const float* bg[4] = {(const float*)d_in[10], (const float*)d_in[14],
                        (const float*)d_in[18], (const float*)d_in[22]};
  int n = in_sizes[0] / 3;
  int e = in_sizes[2] / 2;
  const int* src = ei;
  const int* dst = ei + e;

  char* p = (char*)d_ws;
  auto alloc = [&](size_t bytes) -> void* {
    void* r = (void*)p;
    p += (bytes + 255) & ~(size_t)255;
    return r;
  };
  f16*   xa     = (f16*)alloc((size_t)n*DD*2);
  f16*   xb     = (f16*)alloc((size_t)n*DD*2);
  f16*   agg    = (f16*)alloc((size_t)n*768*2 + 131072);  // slack for tail-tile OOB reads
  f16*   qcsr   = (f16*)alloc((size_t)e*HH*2);
  f16*   wcb    = (f16*)alloc((size_t)4*HH*DD*DD*2);
  float* zbuf   = (float*)alloc((size_t)n*HH*4);
  float* invdeg = (float*)alloc((size_t)n*4);
  int*   cnt    = (int*)alloc((size_t)n*4);
  int*   rowptr = (int*)alloc((size_t)(n+1)*4);
  int*   fc     = (int*)alloc((size_t)n*4);
  int*   esrc   = (int*)alloc((size_t)e*4);
  int*   epos   = (int*)alloc((size_t)e*4);
  int*   bsum   = (int*)alloc(4096);

  hipMemsetAsync(cnt, 0, (size_t)n*4, stream);
  hipMemsetAsync(fc,  0, (size_t)n*4, stream);

  int eb = (e + 255)/256;
  int nb = (n + 255)/256;

  enc_kernel<<<n, 128, 0, stream>>>(pos, nrm, w1, b1, xa, n);
  hist_kernel<<<eb, 256, 0, stream>>>(dst, e, cnt);
  wc4_kernel<<<(4*HH*DD*DD + 255)/256, 256, 0, stream>>>(Wg[0], Wg[1], Wg[2], Wg[3], wcb);
  scan_blk_kernel<<<nb, 256, 0, stream>>>(cnt, rowptr, bsum, n);
  scan_top_kernel<<<1, 256, 0, stream>>>(bsum, nb);
  scan_add_kernel<<<nb, 256, 0, stream>>>(rowptr, bsum, cnt, invdeg, n, e);
  fill_kernel<<<eb, 256, 0, stream>>>(src, dst, e, rowptr, fc, esrc, epos);

  f16* xin = xa;
  f16* xout = xb;
  for (int l = 0; l < 4; l++) {
    z_kernel<<<(n+3)/4, 256, 0, stream>>>(xin, uu[l], zbuf, n);
    q_kernel<<<eb, 256, 0, stream>>>(src, dst, zbuf, cc[l], invdeg, epos, qcsr, e);
    agg_kernel<<<(n+3)/4, 256, 0, stream>>>(xin, qcsr, rowptr, esrc, agg, n);
    gemm_kernel<<<(n+127)/128, 256, 0, stream>>>(agg, wcb + (size_t)l*HH*DD*DD, bg[l], xout, n);
    f16* t = xin; xin = xout; xout = t;
  }
  fin_kernel<<<(n+3)/4, 256, 0, stream>>>(xin, w2, b2, (float*)d_out, n);
}

// Round 10
// 625.103 us; speedup vs baseline: 2.3075x; 1.0920x over previous
//
#include <hip/hip_runtime.h>
#include <hip/hip_fp16.h>

#define DD 128
#define HH 6

typedef _Float16 f16;
typedef _Float16 f16x2 __attribute__((ext_vector_type(2)));
typedef _Float16 f16x8 __attribute__((ext_vector_type(8)));
typedef float f32x4 __attribute__((ext_vector_type(4)));

// ---------------- encoder: x = relu([pos,norm] @ w1.T + b1) -> fp16 ----------------
__global__ void enc_kernel(const float* __restrict__ pos, const float* __restrict__ nrm,
                           const float* __restrict__ w1, const float* __restrict__ b1,
                           f16* __restrict__ x, int n) {
  int i = blockIdx.x;
  int d = threadIdx.x;
  if (i >= n) return;
  float in[6];
  in[0] = pos[i*3+0]; in[1] = pos[i*3+1]; in[2] = pos[i*3+2];
  in[3] = nrm[i*3+0]; in[4] = nrm[i*3+1]; in[5] = nrm[i*3+2];
  const float* wr = w1 + d*6;
  float acc = b1[d];
  #pragma unroll
  for (int k = 0; k < 6; k++) acc = fmaf(in[k], wr[k], acc);
  x[(size_t)i*DD + d] = (f16)fmaxf(acc, 0.0f);
}

// ---------------- degree histogram ----------------
__global__ void hist_kernel(const int* __restrict__ dst, int e, int* __restrict__ cnt) {
  int i = blockIdx.x*blockDim.x + threadIdx.x;
  if (i < e) atomicAdd(&cnt[dst[i]], 1);
}

// ---------------- exclusive scan (3 kernels) ----------------
__global__ void scan_blk_kernel(const int* __restrict__ cnt, int* __restrict__ rowptr,
                                int* __restrict__ bsum, int n) {
  __shared__ int s[256];
  int tid = threadIdx.x;
  int i = blockIdx.x*256 + tid;
  int v = (i < n) ? cnt[i] : 0;
  s[tid] = v; __syncthreads();
  #pragma unroll
  for (int off = 1; off < 256; off <<= 1) {
    int t = (tid >= off) ? s[tid-off] : 0;
    __syncthreads();
    s[tid] += t;
    __syncthreads();
  }
  if (i < n) rowptr[i] = s[tid] - v;
  if (tid == 255) bsum[blockIdx.x] = s[255];
}

__global__ void scan_top_kernel(int* bsum, int nb) {
  __shared__ int s[256];
  int tid = threadIdx.x;
  int v = (tid < nb) ? bsum[tid] : 0;
  s[tid] = v; __syncthreads();
  #pragma unroll
  for (int off = 1; off < 256; off <<= 1) {
    int t = (tid >= off) ? s[tid-off] : 0;
    __syncthreads();
    s[tid] += t;
    __syncthreads();
  }
  if (tid < nb) bsum[tid] = s[tid] - v;
}

// rowptr finalize + invdeg fused
__global__ void scan_add_kernel(int* rowptr, const int* __restrict__ bsum,
                                const int* __restrict__ cnt, float* __restrict__ invdeg,
                                int n, int e) {
  int i = blockIdx.x*256 + threadIdx.x;
  if (i < n) {
    rowptr[i] += bsum[blockIdx.x];
    invdeg[i] = 1.0f / (float)max(cnt[i], 1);
  }
  if (i == 0) rowptr[n] = e;
}

// ---------------- CSR fill: sd_pair[p] = {src, dst}  (single 8B scatter/edge) ----------------
__global__ void fill_kernel(const int* __restrict__ src, const int* __restrict__ dst, int e,
                            const int* __restrict__ rowptr, int* __restrict__ fc,
                            int2* __restrict__ sd_pair) {
  int i = blockIdx.x*blockDim.x + threadIdx.x;
  if (i >= e) return;
  int dd = dst[i];
  int p = rowptr[dd] + atomicAdd(&fc[dd], 1);
  sd_pair[p] = make_int2(src[i], dd);
}

// ---------------- z = x @ u.T  [N,6]  (x fp16) ----------------
__global__ void z_kernel(const f16* __restrict__ x, const float* __restrict__ u,
                         float* __restrict__ z, int n) {
  int node = blockIdx.x*4 + (threadIdx.x >> 6);
  int l = threadIdx.x & 63;
  if (node >= n) return;
  f16x2 v = *(const f16x2*)&x[(size_t)node*DD + 2*l];
  float vx = (float)v[0], vy = (float)v[1];
  float p[HH];
  #pragma unroll
  for (int h = 0; h < HH; h++) {
    float2 uv = *(const float2*)&u[h*DD + 2*l];
    p[h] = vx*uv.x + vy*uv.y;
  }
  #pragma unroll
  for (int off = 32; off; off >>= 1) {
    #pragma unroll
    for (int h = 0; h < HH; h++) p[h] += __shfl_xor(p[h], off, 64);
  }
  if (l == 0) {
    #pragma unroll
    for (int h = 0; h < HH; h++) z[(size_t)node*HH + h] = p[h];
  }
}

// ---------------- per-slot softmax -> fp16 q sequential (deg-divide folded) ----------------
// iterates CSR slots: sequential sd_pair read, sequential qcsr write; only z/invdeg gather
__global__ void q_kernel(const int2* __restrict__ sd_pair,
                         const float* __restrict__ z, const float* __restrict__ c,
                         const float* __restrict__ invdeg,
                         f16* __restrict__ qcsr, int e) {
  int i = blockIdx.x*blockDim.x + threadIdx.x;
  if (i >= e) return;
  int2 sd = sd_pair[i];
  int s = sd.x, dd = sd.y;
  float l[HH];
  float m = -1e30f;
  #pragma unroll
  for (int h = 0; h < HH; h++) {
    l[h] = z[(size_t)s*HH + h] - z[(size_t)dd*HH + h] + c[h];
    m = fmaxf(m, l[h]);
  }
  float sum = 0.f;
  #pragma unroll
  for (int h = 0; h < HH; h++) { l[h] = __expf(l[h] - m); sum += l[h]; }
  float r = invdeg[dd] / sum;
  size_t p = (size_t)i*HH;
  f16x2 o0 = {(f16)(l[0]*r), (f16)(l[1]*r)};
  f16x2 o1 = {(f16)(l[2]*r), (f16)(l[3]*r)};
  f16x2 o2 = {(f16)(l[4]*r), (f16)(l[5]*r)};
  *(f16x2*)&qcsr[p+0] = o0;
  *(f16x2*)&qcsr[p+2] = o1;
  *(f16x2*)&qcsr[p+4] = o2;
}

// ---------------- CSR aggregation: agg[i][h*128+d] = sum_p q[p][h]*x[src_p][d] ----------------
// unroll-4 edge loop (MLP), nontemporal agg stores (no RFO)
__global__ __launch_bounds__(256) void agg_kernel(const f16* __restrict__ x,
                           const f16* __restrict__ qcsr,
                           const int* __restrict__ rowptr, const int2* __restrict__ sd_pair,
                           f16* __restrict__ agg, int n) {
  int node = blockIdx.x*4 + (threadIdx.x >> 6);
  int t = threadIdx.x & 63;
  if (node >= n) return;
  float acc0[HH] = {0,0,0,0,0,0};
  float acc1[HH] = {0,0,0,0,0,0};
  int p0 = rowptr[node], p1 = rowptr[node+1];
  int p = p0;
  for (; p + 4 <= p1; p += 4) {
    int s[4];
    #pragma unroll
    for (int u = 0; u < 4; u++) s[u] = sd_pair[p+u].x;
    f16x2 xv[4];
    #pragma unroll
    for (int u = 0; u < 4; u++) xv[u] = *(const f16x2*)&x[(size_t)s[u]*DD + 2*t];
    const f16x2* qp = (const f16x2*)(qcsr + (size_t)p*HH);
    f16x2 qv[12];
    #pragma unroll
    for (int u = 0; u < 12; u++) qv[u] = qp[u];
    #pragma unroll
    for (int u = 0; u < 4; u++) {
      float x0 = (float)xv[u][0], x1 = (float)xv[u][1];
      float qh[HH] = {(float)qv[u*3+0][0], (float)qv[u*3+0][1],
                      (float)qv[u*3+1][0], (float)qv[u*3+1][1],
                      (float)qv[u*3+2][0], (float)qv[u*3+2][1]};
      #pragma unroll
      for (int h = 0; h < HH; h++) {
        acc0[h] = fmaf(qh[h], x0, acc0[h]);
        acc1[h] = fmaf(qh[h], x1, acc1[h]);
      }
    }
  }
  for (; p < p1; p++) {
    int s = sd_pair[p].x;
    const f16x2* qp = (const f16x2*)(qcsr + (size_t)p*HH);
    f16x2 q01 = qp[0], q23 = qp[1], q45 = qp[2];
    f16x2 xv = *(const f16x2*)&x[(size_t)s*DD + 2*t];
    float x0 = (float)xv[0], x1 = (float)xv[1];
    float qh[HH] = {(float)q01[0], (float)q01[1], (float)q23[0],
                    (float)q23[1], (float)q45[0], (float)q45[1]};
    #pragma unroll
    for (int h = 0; h < HH; h++) {
      acc0[h] = fmaf(qh[h], x0, acc0[h]);
      acc1[h] = fmaf(qh[h], x1, acc1[h]);
    }
  }
  #pragma unroll
  for (int h = 0; h < HH; h++) {
    f16x2 o = {(f16)acc0[h], (f16)acc1[h]};
    __builtin_nontemporal_store(__builtin_bit_cast(unsigned, o),
        (unsigned*)&agg[(size_t)node*768 + h*DD + 2*t]);
  }
}

// ---------------- W concat+convert, all 4 layers: Wc[l][nr][h*128+d] = (f16)W_l[h][nr][d] ----------------
__global__ void wc4_kernel(const float* __restrict__ W0, const float* __restrict__ W1,
                           const float* __restrict__ W2, const float* __restrict__ W3,
                           f16* __restrict__ Wc) {
  int id = blockIdx.x*256 + threadIdx.x;
  if (id >= 4*HH*DD*DD) return;
  int l = id / (HH*DD*DD);
  int r = id - l*(HH*DD*DD);
  const float* W = (l == 0) ? W0 : (l == 1) ? W1 : (l == 2) ? W2 : W3;
  int h = r >> 14, rem = r & 16383, nr = rem >> 7, d = rem & 127;
  Wc[(size_t)l*(HH*DD*DD) + (size_t)nr*768 + h*DD + d] = (f16)W[r];
}

// ---------------- MFMA GEMM (m97-style): xout = relu(agg[n,768] @ Wc.T + bias) ----------------
// 128x128 tile, BK=64, double-buffered global_load_lds(16B), XOR-swizzled LDS
// (inverse-swizzle on global source, swizzle on ds_read — both-sides rule).
// 4 waves in 2x2 grid; wave computes 64x64 via 4x4 16x16x32 MFMA frags.
__global__ __launch_bounds__(256) void gemm_kernel(const f16* __restrict__ A,
                                                   const f16* __restrict__ Wc,
                                                   const float* __restrict__ bias,
                                                   f16* __restrict__ xout, int n) {
  __shared__ char lds[65536];           // A: 2 x 16KB, B: 2 x 16KB
  const int t = threadIdx.x;
  const int l = t & 63;
  const int wave = t >> 6;
  const int wr = wave >> 1, wc = wave & 1;
  const int r16 = l & 15, kc = l >> 4;
  const int m0 = blockIdx.x * 128;

  const int sr0 = t >> 3;
  const int scb = (t & 7) * 16;

  auto stage = [&](int ks, int buf) {
    const int k0 = ks * 64;
    char* Ad = lds + buf * 16384 + (size_t)t * 16;
    char* Bd = lds + 32768 + buf * 16384 + (size_t)t * 16;
    #pragma unroll
    for (int i = 0; i < 4; i++) {
      int r = i * 32 + sr0;
      int cs = (scb ^ ((r & 7) << 4)) >> 1;       // source col in elems
      const f16* ga = A  + (size_t)(m0 + r) * 768 + k0 + cs;
      const f16* gb = Wc + (size_t)r * 768 + k0 + cs;
      __builtin_amdgcn_global_load_lds(
          (const __attribute__((address_space(1))) void*)ga,
          (__attribute__((address_space(3))) void*)(Ad + i * 4096), 16, 0, 0);
      __builtin_amdgcn_global_load_lds(
          (const __attribute__((address_space(1))) void*)gb,
          (__attribute__((address_space(3))) void*)(Bd + i * 4096), 16, 0, 0);
    }
  };

  f32x4 acc[4][4];
  #pragma unroll
  for (int m = 0; m < 4; m++)
    #pragma unroll
    for (int nn = 0; nn < 4; nn++) acc[m][nn] = (f32x4){0.f, 0.f, 0.f, 0.f};

  stage(0, 0);
  __syncthreads();

  const int xr = (r16 & 7) << 4;
  for (int ks = 0; ks < 12; ks++) {
    int buf = ks & 1;
    if (ks < 11) stage(ks + 1, buf ^ 1);
    const char* Ab = lds + buf * 16384;
    const char* Bb = lds + 32768 + buf * 16384;
    #pragma unroll
    for (int kk = 0; kk < 2; kk++) {
      int kb = (kk * 64 + kc * 16) ^ xr;
      f16x8 a[4], b[4];
      #pragma unroll
      for (int m = 0; m < 4; m++)
        a[m] = *(const f16x8*)(Ab + (wr*64 + m*16 + r16) * 128 + kb);
      #pragma unroll
      for (int nn = 0; nn < 4; nn++)
        b[nn] = *(const f16x8*)(Bb + (wc*64 + nn*16 + r16) * 128 + kb);
      #pragma unroll
      for (int m = 0; m < 4; m++)
        #pragma unroll
        for (int nn = 0; nn < 4; nn++)
          acc[m][nn] = __builtin_amdgcn_mfma_f32_16x16x32_f16(a[m], b[nn], acc[m][nn], 0, 0, 0);
    }
    __syncthreads();
  }

  #pragma unroll
  for (int nn = 0; nn < 4; nn++) {
    int col = wc*64 + nn*16 + r16;
    float bv = bias[col];
    #pragma unroll
    for (int m = 0; m < 4; m++) {
      int rbase = m0 + wr*64 + m*16 + kc*4;
      #pragma unroll
      for (int rr = 0; rr < 4; rr++) {
        int gm = rbase + rr;
        if (gm < n) xout[(size_t)gm*DD + col] = (f16)fmaxf(acc[m][nn][rr] + bv, 0.f);
      }
    }
  }
}

// ---------------- final: out = x @ w2.T + b2  [N,3] (x fp16) ----------------
__global__ void fin_kernel(const f16* __restrict__ x, const float* __restrict__ w2,
                           const float* __restrict__ b2, float* __restrict__ out, int n) {
  int node = blockIdx.x*4 + (threadIdx.x >> 6);
  int l = threadIdx.x & 63;
  if (node >= n) return;
  f16x2 v = *(const f16x2*)&x[(size_t)node*DD + 2*l];
  float vx = (float)v[0], vy = (float)v[1];
  float p[3];
  #pragma unroll
  for (int o = 0; o < 3; o++) {
    float2 w = *(const float2*)&w2[o*DD + 2*l];
    p[o] = vx*w.x + vy*w.y;
  }
  #pragma unroll
  for (int off = 32; off; off >>= 1) {
    #pragma unroll
    for (int o = 0; o < 3; o++) p[o] += __shfl_xor(p[o], off, 64);
  }
  if (l == 0) {
    #pragma unroll
    for (int o = 0; o < 3; o++) out[(size_t)node*3 + o] = p[o] + b2[o];
  }
}

extern "C" void kernel_launch(void* const* d_in, const int* in_sizes, int n_in,
                              void* d_out, int out_size, void* d_ws, size_t ws_size,
                              hipStream_t stream) {
  const float* pos = (const float*)d_in[0];
  const float* nrm = (const float*)d_in[1];
  const int*   ei  = (const int*)d_in[2];
  const float* w1  = (const float*)d_in[3];
  const float* b1  = (const float*)d_in[4];
  const float* w2  = (const float*)d_in[5];
  const float* b2  = (const float*)d_in[6];
  const float* Wg[4] = {(const float*)d_in[7],  (const float*)d_in[11],
                        (const float*)d_in[15], (const float*)d_in[19]};
  const float* uu[4] = {(const float*)d_in[8],  (const float*)d_in[12],
                        (const float*)d_in[16], (const float*)d_in[20]};
  const float* cc[4] = {(const float*)d_in[9],  (const float*)d_in[13],
                        (const float*)d_in[17], (const float*)d_in[21]};
  const float* bg[4] = {(const float*)d_in[10], (const float*)d_in[14],
                        (const float*)d_in[18], (const float*)d_in[22]};
  int n = in_sizes[0] / 3;
  int e = in_sizes[2] / 2;
  const int* src = ei;
  const int* dst = ei + e;

  char* p = (char*)d_ws;
  auto alloc = [&](size_t bytes) -> void* {
    void* r = (void*)p;
    p += (bytes + 255) & ~(size_t)255;
    return r;
  };
  f16*   xa     = (f16*)alloc((size_t)n*DD*2);
  f16*   xb     = (f16*)alloc((size_t)n*DD*2);
  f16*   agg    = (f16*)alloc((size_t)n*768*2 + 131072);  // slack for tail-tile OOB reads
  f16*   qcsr   = (f16*)alloc((size_t)e*HH*2);
  f16*   wcb    = (f16*)alloc((size_t)4*HH*DD*DD*2);
  float* zbuf   = (float*)alloc((size_t)n*HH*4);
  float* invdeg = (float*)alloc((size_t)n*4);
  int*   cnt    = (int*)alloc((size_t)n*4);
  int*   rowptr = (int*)alloc((size_t)(n+1)*4);
  int*   fc     = (int*)alloc((size_t)n*4);
  int2*  sd_pair= (int2*)alloc((size_t)e*8);
  int*   bsum   = (int*)alloc(4096);

  hipMemsetAsync(cnt, 0, (size_t)n*4, stream);
  hipMemsetAsync(fc,  0, (size_t)n*4, stream);

  int eb = (e + 255)/256;
  int nb = (n + 255)/256;

  enc_kernel<<<n, 128, 0, stream>>>(pos, nrm, w1, b1, xa, n);
  hist_kernel<<<eb, 256, 0, stream>>>(dst, e, cnt);
  wc4_kernel<<<(4*HH*DD*DD + 255)/256, 256, 0, stream>>>(Wg[0], Wg[1], Wg[2], Wg[3], wcb);
  scan_blk_kernel<<<nb, 256, 0, stream>>>(cnt, rowptr, bsum, n);
  scan_top_kernel<<<1, 256, 0, stream>>>(bsum, nb);
  scan_add_kernel<<<nb, 256, 0, stream>>>(rowptr, bsum, cnt, invdeg, n, e);
  fill_kernel<<<eb, 256, 0, stream>>>(src, dst, e, rowptr, fc, sd_pair);

  f16* xin = xa;
  f16* xout = xb;
  for (int l = 0; l < 4; l++) {
    z_kernel<<<(n+3)/4, 256, 0, stream>>>(xin, uu[l], zbuf, n);
    q_kernel<<<eb, 256, 0, stream>>>(sd_pair, zbuf, cc[l], invdeg, qcsr, e);
    agg_kernel<<<(n+3)/4, 256, 0, stream>>>(xin, qcsr, rowptr, sd_pair, agg, n);
    gemm_kernel<<<(n+127)/128, 256, 0, stream>>>(agg, wcb + (size_t)l*HH*DD*DD, bg[l], xout, n);
    f16* t = xin; xin = xout; xout = t;
  }
  fin_kernel<<<(n+3)/4, 256, 0, stream>>>(xin, w2, b2, (float*)d_out, n);
}